// Round 3
// baseline (4598.993 us; speedup 1.0000x reference)
//
#include <hip/hip_runtime.h>
#include <cstdint>
#include <cstddef>

// ---------------- problem constants ----------------
#define V_SZ 50257
#define H_SZ 512
#define S_SZ 128
#define NBEAM 5
#define TMAXX 32
#define TOK_SOS 1
#define TOK_EOS 2
#define NEGINF (-1e9f)

// ---------------- launch shape ----------------
#define GW 256            // decode workgroups (2 per CU)
#define NT 512
#define GENC 16
#define COLS_PER_WG 200   // 256*200 = 51200 >= 50257

// ---------------- barrier ints (start of ws; first 16 KiB memset to 0) ----------------
#define BI_LEAF(l)  ((l)*32)         // 16 leaves of 16 WGs
#define BI_ROOT     544
#define BI_REL(l)   (576 + (l)*32)   // 16 release generations
#define BI_EFLAG    1152             // encoder flags [128][16]

#define FB_OFF 4096   // float offset of data region

// ---------------- float region (fb-relative) ----------------
#define OF_GI    0            // 128*1536
#define OF_ENC   196608       // 128*512
#define OF_EW    262144       // 128*512
#define OF_H2    327680       // [2][5][512]
#define OF_AL    332800       // [5][128]
#define OF_OTOP  333440       // [5][512] flat b*512+j
#define OF_PV    336000       // [256][5][5]
#define OF_PM    342400       // [256][5]
#define OF_PS    343680       // [256][5]
#define OF_SC    344960       // [8]
#define OI_BASE  344968
// ints (relative to ib): pidx 0..6400, tokA 6400, finA 6408, lenA 6416, parA 6424, seqA 6432 (+320)

template <typename T>
__device__ __forceinline__ T aload(const T* p){
  return __hip_atomic_load((T*)p, __ATOMIC_RELAXED, __HIP_MEMORY_SCOPE_AGENT);
}
template <typename T>
__device__ __forceinline__ void astore(T* p, T v){
  __hip_atomic_store(p, v, __ATOMIC_RELAXED, __HIP_MEMORY_SCOPE_AGENT);
}

__device__ __forceinline__ float wredsum(float a){
#pragma unroll
  for (int m = 32; m; m >>= 1) a += __shfl_xor(a, m, 64);
  return a;
}

// fence-free device barrier over GW WGs; last-arriving WG runs tail() before release.
template <typename F>
__device__ __forceinline__ void dbar(int* bi, int wid, F&& tail){
  __shared__ int s_last;
  int mygen = 0;
  __syncthreads();
  if (threadIdx.x == 0){
    int leaf = wid >> 4;
    mygen = aload(bi + BI_REL(leaf));
    __builtin_amdgcn_s_waitcnt(0);
    int lo = __hip_atomic_fetch_add(bi + BI_LEAF(leaf), 1, __ATOMIC_RELAXED, __HIP_MEMORY_SCOPE_AGENT);
    int last = 0;
    if (lo == 15){
      astore(bi + BI_LEAF(leaf), 0);
      __builtin_amdgcn_s_waitcnt(0);
      int ro = __hip_atomic_fetch_add(bi + BI_ROOT, 1, __ATOMIC_RELAXED, __HIP_MEMORY_SCOPE_AGENT);
      if (ro == (GW/16) - 1){
        astore(bi + BI_ROOT, 0);
        last = 1;
      }
    }
    if (!last){
      while (aload(bi + BI_REL(leaf)) == mygen) __builtin_amdgcn_s_sleep(4);
    }
    s_last = last;
  }
  __syncthreads();
  if (s_last){
    tail();
    __syncthreads();
    if (threadIdx.x == 0){
      __builtin_amdgcn_s_waitcnt(0);
#pragma unroll
      for (int l = 0; l < GW/16; ++l) astore(bi + BI_REL(l), mygen + 1);
    }
  }
  __syncthreads();
}

// ================= K1: gi = src_emb @ eWih^T + bih, + beam-state init =================
__global__ __launch_bounds__(256)
void k_gi(const int* __restrict__ toks, const float* __restrict__ emb,
          const float* __restrict__ eWih, const float* __restrict__ ebih,
          float* __restrict__ ws)
{
  float* fb = ws + FB_OFF;
  float* gi = fb + OF_GI;
  const int tid = threadIdx.x, wid = blockIdx.x, lane = tid & 63, wvi = tid >> 6;
  int Wg = wid*4 + wvi;
  for (int it = 0; it < 192; ++it){
    int idx = Wg*192 + it;
    int s = idx / 1536, j = idx - s*1536;
    const float* er = emb + (size_t)toks[s]*H_SZ;
    const float* wr = eWih + (size_t)j*H_SZ;
    float a = 0.f;
#pragma unroll
    for (int u = 0; u < 8; ++u) a += er[u*64+lane]*wr[u*64+lane];
    a = wredsum(a);
    if (lane == 0) gi[idx] = a + ebih[j];
  }
  if (wid == 0){
    float* sc = fb + OF_SC;
    int* ib = (int*)(fb + OI_BASE);
    if (tid < NBEAM){
      sc[tid] = (tid==0) ? 0.f : NEGINF;
      ib[6400+tid] = TOK_SOS; ib[6408+tid] = 0; ib[6416+tid] = 1; ib[6424+tid] = 0;
    }
    for (int q = tid; q < 2*NBEAM*TMAXX; q += 256) ib[6432+q] = 0;
  }
}

// ================= K2: flag-pipelined sequential encoder (16 WGs, no barriers) =================
__global__ __launch_bounds__(NT, 1)
void k_enc(const float* __restrict__ eWhh, const float* __restrict__ ebhh,
           float* __restrict__ ws)
{
  int* bi = (int*)ws;
  float* fb = ws + FB_OFF;
  float* gi = fb + OF_GI;
  float* enc = fb + OF_ENC;
  const int tid = threadIdx.x, wid = blockIdx.x, lane = tid & 63, wvi = tid >> 6;
  const int i0 = wid*32;
  __shared__ float smF[96];

  float wreg[12][8];
#pragma unroll
  for (int dd = 0; dd < 12; ++dd){
    int d = wvi*12 + dd, g = d >> 5, il = d & 31;
    const float* wr = eWhh + (size_t)(g*512 + i0 + il)*H_SZ;
#pragma unroll
    for (int u = 0; u < 8; ++u) wreg[dd][u] = wr[u*64+lane];
  }

  for (int s = 0; s < S_SZ; ++s){
    float hreg[8];
    if (s == 0){
#pragma unroll
      for (int u = 0; u < 8; ++u) hreg[u] = 0.f;
    } else {
      if (tid < 16){
        while (aload(bi + BI_EFLAG + (s-1)*16 + tid) == 0) __builtin_amdgcn_s_sleep(1);
      }
      __syncthreads();
      const float* hp = enc + (size_t)(s-1)*H_SZ;
#pragma unroll
      for (int u = 0; u < 8; ++u) hreg[u] = aload(hp + u*64 + lane);
    }
#pragma unroll
    for (int dd = 0; dd < 12; ++dd){
      float a = 0.f;
#pragma unroll
      for (int u = 0; u < 8; ++u) a += wreg[dd][u]*hreg[u];
      a = wredsum(a);
      if (lane == 0) smF[wvi*12 + dd] = a;
    }
    __syncthreads();
    if (tid < 32){
      int i = i0 + tid;
      float gr = smF[tid], gz = smF[32+tid], gn = smF[64+tid];
      float gir = gi[s*1536 + i], giz = gi[s*1536 + 512 + i], gin = gi[s*1536 + 1024 + i];
      float hprev = (s==0) ? 0.f : aload(enc + (s-1)*H_SZ + i);
      float r = 1.f/(1.f + expf(-(gir + gr + ebhh[i])));
      float z = 1.f/(1.f + expf(-(giz + gz + ebhh[512+i])));
      float n = tanhf(gin + r*(gn + ebhh[1024+i]));
      astore(enc + s*H_SZ + i, (1.f - z)*n + z*hprev);
    }
    __syncthreads();
    if (tid == 0){
      __builtin_amdgcn_s_waitcnt(0);   // h-chunk at L3 before flag
      astore(bi + BI_EFLAG + s*16 + wid, 1);
    }
  }
}

// ================= K3: EW = enc_out @ Wc_bottom =================
__global__ __launch_bounds__(NT)
void k_ew(const float* __restrict__ Wc, float* __restrict__ ws)
{
  float* fb = ws + FB_OFF;
  float* enc = fb + OF_ENC;
  float* EW  = fb + OF_EW;
  const int tid = threadIdx.x, wid = blockIdx.x;
  int jc = wid & 15, sb = wid >> 4;
  int jl = tid & 31, sl = (tid >> 5) & 15;
  int s = sb*16 + sl, j = jc*32 + jl;
  const float* er = enc + (size_t)s*H_SZ;
  const float* wc = Wc + (size_t)512*H_SZ;
  float a = 0.f;
  for (int k = 0; k < 512; ++k) a += er[k]*wc[(size_t)k*H_SZ + j];
  EW[s*H_SZ + j] = a;
}

// ================= K4: persistent decode (256 WGs, 3 barriers/step) =================
__global__ __launch_bounds__(NT, 4)
void k_dec(const float* __restrict__ emb,
           const float* __restrict__ dWih, const float* __restrict__ dWhh,
           const float* __restrict__ dbih, const float* __restrict__ dbhh,
           const float* __restrict__ Wc,  const float* __restrict__ Wv,
           float* __restrict__ out, float* __restrict__ ws)
{
  const int wid = blockIdx.x, tid = threadIdx.x;
  const int lane = tid & 63, wvi = tid >> 6;
  int* bi = (int*)ws;
  float* fb = ws + FB_OFF;
  float* enc  = fb + OF_ENC;
  float* EW   = fb + OF_EW;
  float* h2   = fb + OF_H2;
  float* al   = fb + OF_AL;
  float* otop = fb + OF_OTOP;
  float* pv   = fb + OF_PV;
  float* pm   = fb + OF_PM;
  float* ps   = fb + OF_PS;
  float* sc   = fb + OF_SC;
  int* ib   = (int*)(fb + OI_BASE);
  int* pidx = ib;
  int* tokA = ib + 6400;
  int* finA = ib + 6408;
  int* lenA = ib + 6416;
  int* parA = ib + 6424;
  int* seqA = ib + 6432;   // [2][5][32]

  __shared__ float smF[2048];
  __shared__ int   smI[256];
  __shared__ float s_buf[2560];
  __shared__ float s_pp[648];

  for (int t = 0; t < TMAXX; ++t){
    float* h2new = h2 + (t & 1)*2560;
    float* h2old = h2 + ((t & 1) ^ 1)*2560;

    // ---- Stage A: decoder GRU (WGs 0..127, each owns 4 i x 5 beams) ----
    if (wid < 128){
      if (tid < NBEAM){ smI[tid] = aload(tokA + tid); smI[8 + tid] = t ? aload(parA + tid) : 0; }
      __syncthreads();
      if (t == 0){
        for (int q = tid; q < 2560; q += NT) s_buf[q] = enc[127*H_SZ + (q & 511)];
      } else {
        for (int q = tid; q < 2560; q += NT){
          int b = q >> 9;
          s_buf[q] = aload(h2old + smI[8 + b]*H_SZ + (q & 511));
        }
      }
      __syncthreads();
      int i0 = wid*4;
      int mat = wvi >> 2;
      float srg[5][8];
      if (mat == 0){
#pragma unroll
        for (int b = 0; b < NBEAM; ++b){
          const float* sp = emb + (size_t)smI[b]*H_SZ;
#pragma unroll
          for (int u = 0; u < 8; ++u) srg[b][u] = sp[u*64+lane];
        }
      } else {
#pragma unroll
        for (int b = 0; b < NBEAM; ++b)
#pragma unroll
          for (int u = 0; u < 8; ++u) srg[b][u] = s_buf[b*512 + u*64 + lane];
      }
      for (int rr = 0; rr < 3; ++rr){
        int R = wvi*3 + rr;
        int rem = R - mat*12;
        int g = rem >> 2, il = rem & 3;
        const float* wr = ((mat==0) ? dWih : dWhh) + (size_t)(g*512 + i0 + il)*H_SZ;
        float wreg[8];
#pragma unroll
        for (int u = 0; u < 8; ++u) wreg[u] = wr[u*64+lane];
#pragma unroll
        for (int b = 0; b < NBEAM; ++b){
          float a = 0.f;
#pragma unroll
          for (int u = 0; u < 8; ++u) a += wreg[u]*srg[b][u];
          a = wredsum(a);
          if (lane == 0) smF[R*5 + b] = a;
        }
      }
      __syncthreads();
      if (tid < 20){
        int b = tid >> 2, il = tid & 3;
        int i = i0 + il;
        float ir  = smF[(0*12 + 0*4 + il)*5 + b] + dbih[i];
        float iz  = smF[(0*12 + 1*4 + il)*5 + b] + dbih[512+i];
        float inn = smF[(0*12 + 2*4 + il)*5 + b] + dbih[1024+i];
        float hr  = smF[(1*12 + 0*4 + il)*5 + b] + dbhh[i];
        float hz  = smF[(1*12 + 1*4 + il)*5 + b] + dbhh[512+i];
        float hn  = smF[(1*12 + 2*4 + il)*5 + b] + dbhh[1024+i];
        float r = 1.f/(1.f + expf(-(ir + hr)));
        float z = 1.f/(1.f + expf(-(iz + hz)));
        float n = tanhf(inn + r*hn);
        float hp = s_buf[b*512 + i];
        astore(h2new + b*H_SZ + i, (1.f - z)*n + z*hp);
      }
    }
    dbar(bi, wid, [&](){});

    // ---- Stage B: attention logits (s = wid < 128) + otop (10 outputs/WG) ----
    for (int q = tid; q < 2560; q += NT) s_buf[q] = aload(h2new + q);
    __syncthreads();
    if (wid < 128 && wvi < NBEAM){
      const float* er = enc + (size_t)wid*H_SZ;
      float a = 0.f;
#pragma unroll
      for (int u = 0; u < 8; ++u) a += er[u*64+lane]*s_buf[wvi*512 + u*64 + lane];
      a = wredsum(a);
      if (lane == 0) astore(al + wvi*S_SZ + wid, a);
    }
    if (tid < 160){
      int q = tid % 10, ksl = tid / 10;
      int f = wid*10 + q;
      int b = f >> 9, j = f & 511;
      float a = 0.f;
#pragma unroll 8
      for (int u = 0; u < 32; ++u){
        int k = ksl*32 + u;
        a += s_buf[b*512 + k]*Wc[(size_t)k*H_SZ + j];
      }
      smF[q*16 + ksl] = a;
    }
    __syncthreads();
    if (tid < 10){
      float a = 0.f;
#pragma unroll
      for (int u = 0; u < 16; ++u) a += smF[tid*16 + u];
      astore(otop + wid*10 + tid, a);
    }
    dbar(bi, wid, [&](){});

    // ---- Stage C: local softmax + o, vocab GEMM (row-split), per-WG partials ----
    if (wvi < NBEAM){
      float a1 = aload(al + wvi*S_SZ + lane), a2 = aload(al + wvi*S_SZ + 64 + lane);
      float m = fmaxf(a1, a2);
#pragma unroll
      for (int mm = 32; mm; mm >>= 1) m = fmaxf(m, __shfl_xor(m, mm, 64));
      float e1 = expf(a1 - m), e2 = expf(a2 - m);
      s_pp[wvi*128 + lane] = e1; s_pp[wvi*128 + 64 + lane] = e2;
      float ssv = wredsum(e1 + e2);
      if (lane == 0) s_pp[640 + wvi] = ssv;
    }
    __syncthreads();
    {
      float acc[5] = {0.f,0.f,0.f,0.f,0.f};
      for (int s2 = 0; s2 < 128; ++s2){
        float e = EW[(size_t)s2*H_SZ + tid];
#pragma unroll
        for (int b = 0; b < NBEAM; ++b) acc[b] += e*s_pp[b*128 + s2];
      }
      float ov[5];
#pragma unroll
      for (int b = 0; b < NBEAM; ++b)
        ov[b] = tanhf(aload(otop + b*512 + tid) + acc[b]/s_pp[640 + b]);
      __syncthreads();
#pragma unroll
      for (int b = 0; b < NBEAM; ++b) s_buf[b*512 + tid] = ov[b];
    }
    __syncthreads();
    {
      const int c = tid & 255;
      const int half = tid >> 8;
      const int vbase = wid*COLS_PER_WG;
      const int v = vbase + c;
      const bool act = (c < COLS_PER_WG) && (v < V_SZ);
      const int vc = act ? v : (V_SZ - 1);
      const float* wp = Wv + vc;
      const int r0 = half*256;
      float acc[5] = {0.f,0.f,0.f,0.f,0.f};
      for (int hb = r0; hb < r0 + 256; hb += 16){
        float wr[16];
#pragma unroll
        for (int u = 0; u < 16; ++u) wr[u] = __builtin_nontemporal_load(wp + (size_t)(hb+u)*V_SZ);
#pragma unroll
        for (int u = 0; u < 16; ++u){
          float w = wr[u];
          acc[0] += w*s_buf[hb+u];
          acc[1] += w*s_buf[512+hb+u];
          acc[2] += w*s_buf[1024+hb+u];
          acc[3] += w*s_buf[1536+hb+u];
          acc[4] += w*s_buf[2048+hb+u];
        }
      }
      if (c < COLS_PER_WG){
#pragma unroll
        for (int b = 0; b < NBEAM; ++b) smF[(half*COLS_PER_WG + c)*5 + b] = acc[b];
      }
      __syncthreads();
      float x5[5]; int myv = 0x7FFFFFFF;
      bool act2 = (tid < COLS_PER_WG) && (vbase + tid < V_SZ);
      if (tid < 256){
#pragma unroll
        for (int b = 0; b < NBEAM; ++b)
          x5[b] = act2 ? (smF[tid*5 + b] + smF[(COLS_PER_WG + tid)*5 + b]) : -3e38f;
        if (act2) myv = vbase + tid;
      }
      __syncthreads();
      if (wvi < 4){
#pragma unroll
        for (int b = 0; b < NBEAM; ++b){
          float x = x5[b];
          float m = x;
#pragma unroll
          for (int mm = 32; mm; mm >>= 1) m = fmaxf(m, __shfl_xor(m, mm, 64));
          float e = expf(x - m);
          float ssum = wredsum(e);
          float bv = x; int bc = myv;
          float w5[5]; int i5[5];
#pragma unroll
          for (int r = 0; r < 5; ++r){
            float cv2 = bv; int ci2 = bc;
#pragma unroll
            for (int mm = 32; mm; mm >>= 1){
              float ovl = __shfl_xor(cv2, mm, 64); int oi = __shfl_xor(ci2, mm, 64);
              bool take = (ovl > cv2) || (ovl == cv2 && oi < ci2);
              cv2 = take ? ovl : cv2; ci2 = take ? oi : ci2;
            }
            w5[r] = cv2; i5[r] = ci2;
            if (bc == ci2) bv = -3e38f;
          }
          if (lane == 0){
#pragma unroll
            for (int r = 0; r < 5; ++r){ smF[(wvi*5+b)*5+r] = w5[r]; smI[(wvi*5+b)*5+r] = i5[r]; }
            smF[600 + wvi*5 + b] = m;
            smF[700 + wvi*5 + b] = ssum;
          }
        }
      }
      __syncthreads();
      if (tid < NBEAM){
        float M = -3.4e38f, Sv = 0.f;
#pragma unroll
        for (int w4 = 0; w4 < 4; ++w4){
          float m2 = smF[600 + w4*5 + tid], s2 = smF[700 + w4*5 + tid];
          if (m2 > M){ Sv = Sv*expf(M - m2) + s2; M = m2; }
          else       { Sv = Sv + s2*expf(m2 - M); }
        }
        astore(pm + wid*5 + tid, M); astore(ps + wid*5 + tid, Sv);
      }
      if (wvi < NBEAM){
        int b = wvi;
        float cval; int cidx;
        if (lane < 20){ cval = smF[((lane/5)*5 + b)*5 + (lane%5)]; cidx = smI[((lane/5)*5 + b)*5 + (lane%5)]; }
        else { cval = -3e38f; cidx = 0x7FFFFFFF; }
        float bv = cval; int bc = cidx;
#pragma unroll
        for (int r = 0; r < 5; ++r){
          float cv2 = bv; int ci2 = bc;
#pragma unroll
          for (int mm = 32; mm; mm >>= 1){
            float ovl = __shfl_xor(cv2, mm, 64); int oi = __shfl_xor(ci2, mm, 64);
            bool take = (ovl > cv2) || (ovl == cv2 && oi < ci2);
            cv2 = take ? ovl : cv2; ci2 = take ? oi : ci2;
          }
          if (lane == 0){ astore(pv + (wid*5+b)*5+r, cv2); astore(pidx + (wid*5+b)*5+r, ci2); }
          if (bc == ci2) bv = -3e38f;
        }
      }
    }
    dbar(bi, wid, [&](){
      // ======== Stage D (tail, one WG): merge 256 WG partials, top-k, state update ========
      int b5 = wvi;
      if (b5 < NBEAM){
        float M = aload(pm + lane*5 + b5), Sv = aload(ps + lane*5 + b5);
#pragma unroll
        for (int g = 1; g < 4; ++g){
          float m2 = aload(pm + (g*64+lane)*5 + b5), s2 = aload(ps + (g*64+lane)*5 + b5);
          if (m2 > M){ Sv = Sv*expf(M - m2) + s2; M = m2; }
          else       { Sv = Sv + s2*expf(m2 - M); }
        }
#pragma unroll
        for (int mm = 32; mm; mm >>= 1){
          float om = __shfl_xor(M, mm, 64), os = __shfl_xor(Sv, mm, 64);
          if (om > M){ Sv = Sv*expf(M - om) + os; M = om; }
          else       { Sv = Sv + os*expf(om - M); }
        }
        if (lane == 0){ smF[8 + b5] = M; smF[80 + b5] = logf(Sv); }
        float lv[5]; int li[5];
#pragma unroll
        for (int r = 0; r < 5; ++r){ lv[r] = aload(pv + (lane*5 + b5)*5 + r); li[r] = aload(pidx + (lane*5 + b5)*5 + r); }
#pragma unroll
        for (int g = 1; g < 4; ++g){
          for (int r = 0; r < 5; ++r){
            float nv = aload(pv + ((g*64+lane)*5 + b5)*5 + r); int ni = aload(pidx + ((g*64+lane)*5 + b5)*5 + r);
            bool ins = (nv > lv[4]) || (nv == lv[4] && ni < li[4]);
            if (!ins) break;
            lv[4] = nv; li[4] = ni;
#pragma unroll
            for (int p = 4; p > 0; --p){
              bool sw = (lv[p] > lv[p-1]) || (lv[p] == lv[p-1] && li[p] < li[p-1]);
              if (sw){ float tv = lv[p]; lv[p] = lv[p-1]; lv[p-1] = tv;
                       int ti = li[p]; li[p] = li[p-1]; li[p-1] = ti; }
            }
          }
        }
        float cv = lv[0]; int ci = li[0];
#pragma unroll
        for (int r = 0; r < 5; ++r){
          float xv = cv; int xi = ci;
#pragma unroll
          for (int mm = 32; mm; mm >>= 1){
            float ovl = __shfl_xor(xv, mm, 64); int oi = __shfl_xor(xi, mm, 64);
            bool take = (ovl > xv) || (ovl == xv && oi < xi);
            xv = take ? ovl : xv; xi = take ? oi : xi;
          }
          if (lane == 0){ smF[16 + b5*5 + r] = xv; smI[16 + b5*5 + r] = xi; }
          if (ci == xi){
            lv[0]=lv[1]; li[0]=li[1]; lv[1]=lv[2]; li[1]=li[2];
            lv[2]=lv[3]; li[2]=li[3]; lv[3]=lv[4]; li[3]=li[4];
            lv[4] = -3e38f; li[4] = 0x7FFFFFFF;
            cv = lv[0]; ci = li[0];
          }
        }
      }
      __syncthreads();
      if (wvi == 0){
        float cval = -3e38f; int cflat = 0x7FFFFFFF;
        int b = lane/5, k = lane - b*5;
        if (lane < 25){
          if (aload(finA + b)){
            if (k == 0){ cval = aload(sc + b) + 0.0f; cflat = b*V_SZ + TOK_EOS; }
          } else {
            cval = ((smF[16 + b*5 + k] - smF[8 + b]) - smF[80 + b]) + aload(sc + b);
            cflat = b*V_SZ + smI[16 + b*5 + k];
          }
        }
        float bv = cval; int bc = cflat;
#pragma unroll
        for (int r = 0; r < 5; ++r){
          float xv = bv; int xi = bc;
#pragma unroll
          for (int mm = 32; mm; mm >>= 1){
            float ovl = __shfl_xor(xv, mm, 64); int oi = __shfl_xor(xi, mm, 64);
            bool take = (ovl > xv) || (ovl == xv && oi < xi);
            xv = take ? ovl : xv; xi = take ? oi : xi;
          }
          if (lane == 0){ smF[48 + r] = xv; smI[48 + r] = xi; }
          if (bc == xi) bv = -3e38f;
        }
        if (lane < NBEAM){
          int r = lane;
          float nscore = smF[48 + r]; int nfl = smI[48 + r];
          int par = nfl / V_SZ; int tok = nfl - par*V_SZ;
          int ofin = aload(finA + par); int olen = aload(lenA + par);
          int nf = (ofin || tok == TOK_EOS) ? 1 : 0;
          int nl = olen + (ofin ? 0 : 1);
          astore(sc + r, nscore); astore(tokA + r, tok); astore(finA + r, nf);
          astore(lenA + r, nl); astore(parA + r, par);
          smI[56 + r] = par; smI[64 + r] = tok; smI[72 + r] = ofin; smI[80 + r] = nl;
          smF[56 + r] = nscore;
        }
      }
      __syncthreads();
      int cur = t & 1, nxt = 1 - cur;
      if (tid < 160){
        int r = tid >> 5, u = tid & 31;
        int par = smI[56 + r];
        int val = aload(seqA + cur*160 + par*32 + u);
        if (u == t) val = smI[72 + r] ? 0 : smI[64 + r];
        astore(seqA + nxt*160 + r*32 + u, val);
      }
      if (t == TMAXX - 1){
        __syncthreads();
        if (tid == 0){
          float nn[5];
#pragma unroll
          for (int r = 0; r < 5; ++r) nn[r] = smF[56 + r] / (float)smI[80 + r];
          int used = 0;
#pragma unroll
          for (int r = 0; r < 5; ++r){
            int best = -1;
            for (int q2 = 0; q2 < 5; ++q2){
              if (used & (1 << q2)) continue;
              if (best < 0 || nn[q2] > nn[best]) best = q2;
            }
            used |= (1 << best);
            smI[88 + r] = best; smF[64 + r] = nn[best];
          }
        }
        __syncthreads();
        if (tid < 160){
          int r = tid >> 5, u = tid & 31;
          int src = smI[88 + r];
          out[tid] = (float)aload(seqA + nxt*160 + src*32 + u);
        }
        if (tid >= 160 && tid < 165) out[tid] = smF[64 + (tid - 160)];
      }
    });
  }
}

extern "C" void kernel_launch(void* const* d_in, const int* in_sizes, int n_in,
                              void* d_out, int out_size, void* d_ws, size_t ws_size,
                              hipStream_t stream)
{
  (void)in_sizes; (void)n_in; (void)out_size; (void)ws_size;
  hipMemsetAsync(d_ws, 0, 16384, stream);
  float* ws = (float*)d_ws;
  k_gi<<<dim3(256), dim3(256), 0, stream>>>(
      (const int*)d_in[0], (const float*)d_in[1],
      (const float*)d_in[2], (const float*)d_in[4], ws);
  k_enc<<<dim3(GENC), dim3(NT), 0, stream>>>(
      (const float*)d_in[3], (const float*)d_in[5], ws);
  k_ew<<<dim3(128), dim3(NT), 0, stream>>>(
      (const float*)d_in[10], ws);
  k_dec<<<dim3(GW), dim3(NT), 0, stream>>>(
      (const float*)d_in[1],
      (const float*)d_in[6], (const float*)d_in[7],
      (const float*)d_in[8], (const float*)d_in[9],
      (const float*)d_in[10], (const float*)d_in[11],
      (float*)d_out, ws);
}